// Round 18
// baseline (697.700 us; speedup 1.0000x reference)
//
#include <hip/hip_runtime.h>

typedef unsigned short u16;
typedef __attribute__((ext_vector_type(8))) short short8;
typedef __attribute__((ext_vector_type(8))) __bf16 bf16x8;
typedef __attribute__((ext_vector_type(4))) float f32x4;

#define DEV __device__ __forceinline__
#define SB() __builtin_amdgcn_sched_barrier(0)

DEV float bf2f(u16 u) {
    union { unsigned v; float f; } x; x.v = ((unsigned)u) << 16; return x.f;
}
DEV u16 f2bf(float f) {
    union { float f; unsigned v; } x; x.f = f;
    unsigned r = x.v + 0x7fff + ((x.v >> 16) & 1);
    return (u16)(r >> 16);
}

DEV f32x4 mfma16(short8 a, short8 b, f32x4 c) {
    return __builtin_amdgcn_mfma_f32_16x16x32_bf16(
        __builtin_bit_cast(bf16x8, a), __builtin_bit_cast(bf16x8, b), c, 0, 0, 0);
}

typedef const __attribute__((address_space(1))) void* gas_ptr;
typedef __attribute__((address_space(3))) void* las_ptr;

// ---------------- Batched transpose: 4x f32 [2048][2048] -> bf16 [2048][2048]^T ----------------
__global__ __launch_bounds__(256) void transpose4_kernel(
    const float* __restrict__ w0, const float* __restrict__ w1,
    const float* __restrict__ w2, const float* __restrict__ w3,
    u16* __restrict__ out)
{
    __shared__ u16 t[64][65];
    int tid = threadIdx.x, z = blockIdx.z;
    const float* in = (z == 0) ? w0 : (z == 1) ? w1 : (z == 2) ? w2 : w3;
    u16* op0 = out + (size_t)z * 4194304ULL;
    int bc = blockIdx.x * 64, br = blockIdx.y * 64;
    int r = tid >> 2, cs = (tid & 3) * 16;
    const float* ip = in + (size_t)(br + r) * 2048 + bc + cs;
    f32x4 v0 = *(const f32x4*)ip, v1 = *(const f32x4*)(ip + 4),
          v2 = *(const f32x4*)(ip + 8), v3 = *(const f32x4*)(ip + 12);
#pragma unroll
    for (int j = 0; j < 4; j++) {
        t[r][cs + j]      = f2bf(v0[j]);
        t[r][cs + 4 + j]  = f2bf(v1[j]);
        t[r][cs + 8 + j]  = f2bf(v2[j]);
        t[r][cs + 12 + j] = f2bf(v3[j]);
    }
    __syncthreads();
    int n = tid >> 2, ks = (tid & 3) * 16;
    short8 o0, o1;
#pragma unroll
    for (int j = 0; j < 8; j++) { o0[j] = (short)t[ks + j][n]; o1[j] = (short)t[ks + 8 + j][n]; }
    u16* op = op0 + (size_t)(bc + n) * 2048 + br + ks;
    *(short8*)op = o0;
    *(short8*)(op + 8) = o1;
}

// ---------------- Transpose: f32 [R][C] -> bf16 [C][R] ----------------
__global__ __launch_bounds__(256) void transpose_kernel(
    const float* __restrict__ in, u16* __restrict__ out, int R, int C)
{
    __shared__ u16 t[64][65];
    int tid = threadIdx.x;
    int bc = blockIdx.x * 64, br = blockIdx.y * 64;
    int r = tid >> 2, cs = (tid & 3) * 16;
    const float* ip = in + (size_t)(br + r) * C + bc + cs;
    f32x4 v0 = *(const f32x4*)ip, v1 = *(const f32x4*)(ip + 4),
          v2 = *(const f32x4*)(ip + 8), v3 = *(const f32x4*)(ip + 12);
#pragma unroll
    for (int j = 0; j < 4; j++) {
        t[r][cs + j]      = f2bf(v0[j]);
        t[r][cs + 4 + j]  = f2bf(v1[j]);
        t[r][cs + 8 + j]  = f2bf(v2[j]);
        t[r][cs + 12 + j] = f2bf(v3[j]);
    }
    __syncthreads();
    int n = tid >> 2, ks = (tid & 3) * 16;
    short8 o0, o1;
#pragma unroll
    for (int j = 0; j < 8; j++) { o0[j] = (short)t[ks + j][n]; o1[j] = (short)t[ks + 8 + j][n]; }
    u16* op = out + (size_t)(bc + n) * R + br + ks;
    *(short8*)op = o0;
    *(short8*)(op + 8) = o1;
}

// ---------------- LayerNorm ----------------
template<int INBF>
__global__ __launch_bounds__(256) void ln_kernel(
    const void* __restrict__ xp, const float* __restrict__ sc, const float* __restrict__ sh,
    u16* __restrict__ out)
{
    int row = blockIdx.x, tid = threadIdx.x;
    float f[8], sum = 0.f, ss = 0.f;
    if (INBF) {
        short8 v = *(const short8*)((const u16*)xp + (size_t)row * 2048 + tid * 8);
#pragma unroll
        for (int j = 0; j < 8; j++) f[j] = bf2f((u16)v[j]);
    } else {
        const f32x4* xr = (const f32x4*)((const float*)xp + (size_t)row * 2048 + tid * 8);
        f32x4 a = xr[0], b = xr[1];
#pragma unroll
        for (int j = 0; j < 4; j++) { f[j] = a[j]; f[4 + j] = b[j]; }
    }
#pragma unroll
    for (int j = 0; j < 8; j++) { sum += f[j]; ss += f[j] * f[j]; }
#pragma unroll
    for (int m = 1; m < 64; m <<= 1) { sum += __shfl_xor(sum, m, 64); ss += __shfl_xor(ss, m, 64); }
    __shared__ float red[8];
    int w = tid >> 6, l = tid & 63;
    if (l == 0) { red[w] = sum; red[4 + w] = ss; }
    __syncthreads();
    sum = red[0] + red[1] + red[2] + red[3];
    ss  = red[4] + red[5] + red[6] + red[7];
    float mean = sum * (1.f / 2048.f);
    float var  = ss * (1.f / 2048.f) - mean * mean;
    float rstd = rsqrtf(var + 1e-5f);
    const f32x4* sp = (const f32x4*)(sc + tid * 8);
    const f32x4* bp = (const f32x4*)(sh + tid * 8);
    f32x4 s0 = sp[0], s1 = sp[1], b0 = bp[0], b1 = bp[1];
    short8 o;
#pragma unroll
    for (int j = 0; j < 4; j++) {
        o[j]     = (short)f2bf((f[j] - mean) * rstd * s0[j] + b0[j]);
        o[4 + j] = (short)f2bf((f[4 + j] - mean) * rstd * s1[j] + b1[j]);
    }
    *(short8*)(out + (size_t)row * 2048 + tid * 8) = o;
}

// ---------------- Producer/consumer GEMM (BN=128, BK=64, ring-3) — r11/r15 proven ----------------
template<int EPI, int OUTF, int RESBF, int SPLITM, int SHAREB>
__global__ __launch_bounds__(576, 1) void gemm_pc(
    const u16* __restrict__ A, const u16* __restrict__ BT, void* __restrict__ Cp,
    const float* __restrict__ bias, const void* __restrict__ res, int M, int N, int K)
{
    __shared__ u16 As[3][256 * 64];
    __shared__ u16 Bs[3][128 * 64];
    int tid = threadIdx.x, l = tid & 63, w = tid >> 6;

    int nbx = gridDim.x, nby = gridDim.y;
    int nwg = nbx * nby;
    int orig = blockIdx.y * nbx + blockIdx.x;
    int wg = (orig & 7) * (nwg >> 3) + (orig >> 3);
    int bx, by;
    if (SHAREB) { bx = wg / nby; by = wg % nby; }
    else        { by = wg / nbx; bx = wg % nbx; }

    int mbase = by * 256, nbase = bx * 128;
    const u16* Ag = A + (size_t)mbase * K;
    const u16* Bg = BT + (size_t)nbase * K;
    int NT = K >> 6;

    if (w == 8) {
        auto pstage = [&](int s, int tt) {
#pragma unroll
            for (int g = 0; g < 32; g++) {
                int c = g * 64 + l;
                int r = c >> 3, ch = (c & 7) ^ (r & 7);
                __builtin_amdgcn_global_load_lds(
                    (gas_ptr)(Ag + (size_t)r * K + tt * 64 + ch * 8),
                    (las_ptr)&As[s][g * 512], 16, 0, 0);
            }
#pragma unroll
            for (int g = 0; g < 16; g++) {
                int c = g * 64 + l;
                int r = c >> 3, ch = (c & 7) ^ (r & 7);
                __builtin_amdgcn_global_load_lds(
                    (gas_ptr)(Bg + (size_t)r * K + tt * 64 + ch * 8),
                    (las_ptr)&Bs[s][g * 512], 16, 0, 0);
            }
        };
        pstage(0, 0); pstage(1, 1);
        asm volatile("s_waitcnt vmcnt(48)" ::: "memory");
        SB();
        __builtin_amdgcn_s_barrier();
        SB();
        for (int t = 0; t < NT; ++t) {
            if (t + 2 < NT) pstage((t + 2) % 3, t + 2);
            if (t + 1 < NT) {
                if (t + 2 < NT) { asm volatile("s_waitcnt vmcnt(48)" ::: "memory"); }
                else            { asm volatile("s_waitcnt vmcnt(0)"  ::: "memory"); }
            }
            SB();
            __builtin_amdgcn_s_barrier();
            SB();
        }
        return;
    }

    int wm = w >> 1, wn = w & 1;
    f32x4 acc[4][4];
#pragma unroll
    for (int i = 0; i < 4; i++)
#pragma unroll
        for (int j = 0; j < 4; j++) acc[i][j] = (f32x4){0.f, 0.f, 0.f, 0.f};

    __builtin_amdgcn_s_barrier();
    SB();
    int slot = 0;
    for (int t = 0; t < NT; ++t) {
        const u16* Ab = &As[slot][0];
        const u16* Bb = &Bs[slot][0];
        short8 af[2][4], bfr[2][4];
#pragma unroll
        for (int ks = 0; ks < 2; ks++) {
            int c = ks * 4 + (l >> 4);
#pragma unroll
            for (int i = 0; i < 4; i++) {
                int ra = wm * 64 + i * 16 + (l & 15);
                af[ks][i] = *(const short8*)&Ab[ra * 64 + ((c ^ (ra & 7)) << 3)];
                int rb = wn * 64 + i * 16 + (l & 15);
                bfr[ks][i] = *(const short8*)&Bb[rb * 64 + ((c ^ (rb & 7)) << 3)];
            }
        }
        __builtin_amdgcn_s_setprio(1);
#pragma unroll
        for (int ks = 0; ks < 2; ks++)
#pragma unroll
            for (int mi = 0; mi < 4; mi++)
#pragma unroll
                for (int ni = 0; ni < 4; ni++)
                    acc[mi][ni] = mfma16(af[ks][mi], bfr[ks][ni], acc[mi][ni]);
        __builtin_amdgcn_s_setprio(0);
        SB();
        __builtin_amdgcn_s_barrier();
        SB();
        slot = (slot == 2) ? 0 : slot + 1;
    }

#pragma unroll
    for (int mi = 0; mi < 4; mi++) {
#pragma unroll
        for (int ni = 0; ni < 4; ni++) {
            int col = nbase + wn * 64 + ni * 16 + (l & 15);
            float bval = (EPI != 0) ? bias[col] : 0.f;
#pragma unroll
            for (int r = 0; r < 4; r++) {
                int row = mbase + wm * 64 + mi * 16 + (l >> 4) * 4 + r;
                float v = acc[mi][ni][r];
                if (EPI == 1) {
                    size_t ridx = (size_t)row * N + col;
                    float rv = RESBF ? bf2f(((const u16*)res)[ridx]) : ((const float*)res)[ridx];
                    v += bval + rv;
                }
                if (EPI == 2) {
                    v += bval;
                    float tt = tanhf(0.7978845608028654f * (v + 0.044715f * v * v * v));
                    v = 0.5f * v * (1.f + tt);
                }
                if (SPLITM == 1) {
                    ((u16*)Cp)[(size_t)(col >> 11) * 8388608ULL + (size_t)row * 2048 + (col & 2047)] = f2bf(v);
                } else if (SPLITM == 2) {
                    ((u16*)Cp)[(size_t)(col >> 11) * 4194304ULL + (size_t)row * 2048 + (col & 2047)] = f2bf(v);
                } else if (OUTF) {
                    ((float*)Cp)[(size_t)row * N + col] = v;
                } else {
                    ((u16*)Cp)[(size_t)row * N + col] = f2bf(v);
                }
            }
        }
    }
}

// ---------------- Hybrid-producer GEMM: 256x256 tile, BK=32, ring-3 (96KB) ----------------
// 512 thr = 8 waves (4M x 2N, per-wave 64x128). Wave 0 also stages (32 gload_lds/tile)
// and is the only wave touching vmcnt. 1 B staged per 131 FLOP (3x gemm_pc).
template<int EPI, int OUTF, int RESBF, int SPLITM>
__global__ __launch_bounds__(512, 1) void gemm_ht(
    const u16* __restrict__ A, const u16* __restrict__ BT, void* __restrict__ Cp,
    const float* __restrict__ bias, const void* __restrict__ res, int M, int N, int K)
{
    __shared__ u16 As[3][256 * 32];
    __shared__ u16 Bs[3][256 * 32];
    int tid = threadIdx.x, l = tid & 63, w = tid >> 6;
    int wm = w >> 1, wn = w & 1;

    int nbx = gridDim.x, nby = gridDim.y;
    int nwg = nbx * nby;
    int orig = blockIdx.y * nbx + blockIdx.x;
    int wg = (orig & 7) * (nwg >> 3) + (orig >> 3);
    int bx = wg / nby, by = wg % nby;   // share-B walk

    int mbase = by * 256, nbase = bx * 256;
    const u16* Ag = A + (size_t)mbase * K;
    const u16* Bg = BT + (size_t)nbase * K;
    int NT = K >> 5;

    // wave-0 staging: 16 loads A + 16 loads B (256 rows x 32 cols each)
    auto stage = [&](int s, int tt) {
#pragma unroll
        for (int g = 0; g < 16; g++) {
            int c = g * 64 + l;
            int r = c >> 2, ch = (c & 3) ^ ((r >> 1) & 3);
            __builtin_amdgcn_global_load_lds(
                (gas_ptr)(Ag + (size_t)r * K + tt * 32 + ch * 8),
                (las_ptr)&As[s][g * 512], 16, 0, 0);
        }
#pragma unroll
        for (int g = 0; g < 16; g++) {
            int c = g * 64 + l;
            int r = c >> 2, ch = (c & 3) ^ ((r >> 1) & 3);
            __builtin_amdgcn_global_load_lds(
                (gas_ptr)(Bg + (size_t)r * K + tt * 32 + ch * 8),
                (las_ptr)&Bs[s][g * 512], 16, 0, 0);
        }
    };

    f32x4 acc[4][8];
#pragma unroll
    for (int i = 0; i < 4; i++)
#pragma unroll
        for (int j = 0; j < 8; j++) acc[i][j] = (f32x4){0.f, 0.f, 0.f, 0.f};

    if (w == 0) {
        stage(0, 0); stage(1, 1);
        asm volatile("s_waitcnt vmcnt(32)" ::: "memory");   // tile 0 landed
    }
    SB();
    __builtin_amdgcn_s_barrier();
    SB();

    int slot = 0;
    for (int t = 0; t < NT; ++t) {
        if (w == 0 && t + 2 < NT) stage((slot == 0) ? 2 : slot - 1, t + 2); // (t+2)%3
        const u16* Ab = &As[slot][0];
        const u16* Bb = &Bs[slot][0];
        short8 af[4], bfr[8];
        int c = l >> 4;
#pragma unroll
        for (int i = 0; i < 4; i++) {
            int ra = wm * 64 + i * 16 + (l & 15);
            af[i] = *(const short8*)&Ab[ra * 32 + ((c ^ ((ra >> 1) & 3)) << 3)];
        }
#pragma unroll
        for (int j = 0; j < 8; j++) {
            int rb = wn * 128 + j * 16 + (l & 15);
            bfr[j] = *(const short8*)&Bb[rb * 32 + ((c ^ ((rb >> 1) & 3)) << 3)];
        }
        __builtin_amdgcn_s_setprio(1);
#pragma unroll
        for (int i = 0; i < 4; i++)
#pragma unroll
            for (int j = 0; j < 8; j++)
                acc[i][j] = mfma16(af[i], bfr[j], acc[i][j]);
        __builtin_amdgcn_s_setprio(0);
        if (w == 0 && t + 1 < NT) {
            if (t + 2 < NT) { asm volatile("s_waitcnt vmcnt(32)" ::: "memory"); }
            else            { asm volatile("s_waitcnt vmcnt(0)"  ::: "memory"); }
        }
        SB();
        __builtin_amdgcn_s_barrier();
        SB();
        slot = (slot == 2) ? 0 : slot + 1;
    }

#pragma unroll
    for (int mi = 0; mi < 4; mi++) {
#pragma unroll
        for (int ni = 0; ni < 8; ni++) {
            int col = nbase + wn * 128 + ni * 16 + (l & 15);
            float bval = (EPI != 0) ? bias[col] : 0.f;
#pragma unroll
            for (int r = 0; r < 4; r++) {
                int row = mbase + wm * 64 + mi * 16 + (l >> 4) * 4 + r;
                float v = acc[mi][ni][r];
                if (EPI == 1) {
                    size_t ridx = (size_t)row * N + col;
                    float rv = RESBF ? bf2f(((const u16*)res)[ridx]) : ((const float*)res)[ridx];
                    v += bval + rv;
                }
                if (EPI == 2) {
                    v += bval;
                    float tt = tanhf(0.7978845608028654f * (v + 0.044715f * v * v * v));
                    v = 0.5f * v * (1.f + tt);
                }
                if (SPLITM == 1) {
                    ((u16*)Cp)[(size_t)(col >> 11) * 8388608ULL + (size_t)row * 2048 + (col & 2047)] = f2bf(v);
                } else if (SPLITM == 2) {
                    ((u16*)Cp)[(size_t)(col >> 11) * 4194304ULL + (size_t)row * 2048 + (col & 2047)] = f2bf(v);
                } else if (OUTF) {
                    ((float*)Cp)[(size_t)row * N + col] = v;
                } else {
                    ((u16*)Cp)[(size_t)row * N + col] = f2bf(v);
                }
            }
        }
    }
}

// ---------------- Causal flash attention: H=16, HD=128, S=2048 ----------------
__global__ __launch_bounds__(256, 2) void attn_kernel(
    const u16* __restrict__ Q, const u16* __restrict__ Kp, const u16* __restrict__ VTg,
    u16* __restrict__ O)
{
    __shared__ u16 Ks[64 * 128];
    __shared__ u16 VT[128 * 64];
    __shared__ u16 Ps[4 * 2048];
    int tid = threadIdx.x, l = tid & 63, w = tid >> 6;
    int qtl = (int)gridDim.x - 1 - (int)blockIdx.x;
    int bh = blockIdx.y, b = bh >> 4, h = bh & 15;
    const float SCALE = 0.08838834764831845f;
    int qbase = qtl * 128;
    size_t bS = (size_t)b * 2048;
    const u16* vrow = VTg + (size_t)bh * 128 * 2048;

    short8 qf[2][4];
#pragma unroll
    for (int mg = 0; mg < 2; mg++) {
        int qrow = qbase + w * 32 + mg * 16 + (l & 15);
        const u16* qp = Q + (bS + qrow) * 2048 + h * 128 + (l >> 4) * 8;
#pragma unroll
        for (int ds = 0; ds < 4; ds++) qf[mg][ds] = *(const short8*)(qp + ds * 32);
    }
    float m_[2][4], l_[2][4];
    f32x4 o_[2][8];
#pragma unroll
    for (int mg = 0; mg < 2; mg++)
#pragma unroll
        for (int r = 0; r < 4; r++) { m_[mg][r] = -1e30f; l_[mg][r] = 0.f; }
#pragma unroll
    for (int mg = 0; mg < 2; mg++)
#pragma unroll
        for (int d = 0; d < 8; d++) o_[mg][d] = (f32x4){0.f, 0.f, 0.f, 0.f};

    int ktmax = 2 * qtl + 1;
    for (int kt = 0; kt <= ktmax; ++kt) {
        int kbase = kt * 64;
#pragma unroll
        for (int it = 0; it < 4; ++it) {
            int slot = it * 256 + tid;
            int key = slot >> 4, dseg = slot & 15;
            short8 kv = *(const short8*)(Kp + (bS + kbase + key) * 2048 + h * 128 + dseg * 8);
            int kidx = ((key * 256 + dseg * 16) ^ ((key & 7) << 4)) >> 1;
            *(short8*)&Ks[kidx] = kv;
            int d = slot >> 3, k8 = slot & 7;
            short8 vv = *(const short8*)(vrow + (size_t)d * 2048 + kbase + k8 * 8);
            int vidx = ((d * 128 + k8 * 16) ^ ((d & 7) << 4)) >> 1;
            *(short8*)&VT[vidx] = vv;
        }
        __syncthreads();

        f32x4 s[2][4];
#pragma unroll
        for (int mg = 0; mg < 2; mg++)
#pragma unroll
            for (int kg = 0; kg < 4; kg++) s[mg][kg] = (f32x4){0.f, 0.f, 0.f, 0.f};
        __builtin_amdgcn_s_setprio(1);
#pragma unroll
        for (int kg = 0; kg < 4; kg++) {
            int key0 = kg * 16 + (l & 15);
#pragma unroll
            for (int ds = 0; ds < 4; ds++) {
                int i0 = ((key0 * 256 + ds * 64 + (l >> 4) * 16) ^ ((key0 & 7) << 4)) >> 1;
                short8 kb = *(const short8*)&Ks[i0];
                s[0][kg] = mfma16(qf[0][ds], kb, s[0][kg]);
                s[1][kg] = mfma16(qf[1][ds], kb, s[1][kg]);
            }
        }
        __builtin_amdgcn_s_setprio(0);

        bool domask = (kbase + 63) > qbase;
        float alpha[2][4];
        bool needresc[2] = {false, false};
        u16* Pw = &Ps[w * 2048];
#pragma unroll
        for (int mg = 0; mg < 2; mg++) {
#pragma unroll
            for (int r = 0; r < 4; r++) {
                int qrow = qbase + w * 32 + mg * 16 + (l >> 4) * 4 + r;
                float aa[4];
#pragma unroll
                for (int kg = 0; kg < 4; kg++) {
                    float a = s[mg][kg][r] * SCALE;
                    if (domask && (kbase + kg * 16 + (l & 15)) > qrow) a = -1e30f;
                    aa[kg] = a;
                }
                float mx = fmaxf(fmaxf(aa[0], aa[1]), fmaxf(aa[2], aa[3]));
                mx = fmaxf(mx, __shfl_xor(mx, 1, 64));
                mx = fmaxf(mx, __shfl_xor(mx, 2, 64));
                mx = fmaxf(mx, __shfl_xor(mx, 4, 64));
                mx = fmaxf(mx, __shfl_xor(mx, 8, 64));
                float mn, al;
                if (mx <= m_[mg][r] + 8.0f) {
                    mn = m_[mg][r]; al = 1.0f;
                } else {
                    mn = mx; al = __expf(m_[mg][r] - mn);
                    needresc[mg] = true;
                }
                m_[mg][r] = mn;
                float p[4], rs = 0.f;
#pragma unroll
                for (int kg = 0; kg < 4; kg++) { p[kg] = __expf(aa[kg] - mn); rs += p[kg]; }
                rs += __shfl_xor(rs, 1, 64);
                rs += __shfl_xor(rs, 2, 64);
                rs += __shfl_xor(rs, 4, 64);
                rs += __shfl_xor(rs, 8, 64);
                l_[mg][r] = l_[mg][r] * al + rs;
                alpha[mg][r] = al;
#pragma unroll
                for (int kg = 0; kg < 4; kg++) {
                    int col = kg * 16 + (l & 15);
                    int lp = ((l >> 4) * 4 + r) | (((col >> 3) & 3) << 4);
                    Pw[(mg * 2 + (col >> 5)) * 512 + lp * 8 + (col & 7)] = f2bf(p[kg]);
                }
            }
        }
        if (__any(needresc[0] || needresc[1])) {
#pragma unroll
            for (int mg = 0; mg < 2; mg++)
#pragma unroll
                for (int dblk = 0; dblk < 8; dblk++)
#pragma unroll
                    for (int r = 0; r < 4; r++) o_[mg][dblk][r] *= alpha[mg][r];
        }

        __builtin_amdgcn_s_setprio(1);
#pragma unroll
        for (int kk = 0; kk < 2; kk++) {
            short8 pa0 = *(const short8*)&Pw[(0 * 2 + kk) * 512 + l * 8];
            short8 pa1 = *(const short8*)&Pw[(1 * 2 + kk) * 512 + l * 8];
#pragma unroll
            for (int dblk = 0; dblk < 8; dblk++) {
                int d = dblk * 16 + (l & 15);
                int iv = ((d * 128 + kk * 64 + (l >> 4) * 16) ^ ((d & 7) << 4)) >> 1;
                short8 vb = *(const short8*)&VT[iv];
                o_[0][dblk] = mfma16(pa0, vb, o_[0][dblk]);
                o_[1][dblk] = mfma16(pa1, vb, o_[1][dblk]);
            }
        }
        __builtin_amdgcn_s_setprio(0);
        __syncthreads();
    }

#pragma unroll
    for (int mg = 0; mg < 2; mg++) {
#pragma unroll
        for (int dblk = 0; dblk < 8; dblk++) {
#pragma unroll
            for (int r = 0; r < 4; r++) {
                int qrow = qbase + w * 32 + mg * 16 + (l >> 4) * 4 + r;
                float v = o_[mg][dblk][r] / l_[mg][r];
                O[(bS + qrow) * 2048 + h * 128 + dblk * 16 + (l & 15)] = f2bf(v);
            }
        }
    }
}

extern "C" void kernel_launch(void* const* d_in, const int* in_sizes, int n_in,
                              void* d_out, int out_size, void* d_ws, size_t ws_size,
                              hipStream_t stream)
{
    const float* x    = (const float*)d_in[0];
    const float* ln1s = (const float*)d_in[1];
    const float* ln1b = (const float*)d_in[2];
    const float* Wq   = (const float*)d_in[3];
    const float* Wk   = (const float*)d_in[4];
    const float* Wv   = (const float*)d_in[5];
    const float* Wo   = (const float*)d_in[6];
    const float* bo   = (const float*)d_in[7];
    const float* ln2s = (const float*)d_in[8];
    const float* ln2b = (const float*)d_in[9];
    const float* W1   = (const float*)d_in[10];
    const float* b1   = (const float*)d_in[11];
    const float* W2   = (const float*)d_in[12];
    const float* b2   = (const float*)d_in[13];
    float* out = (float*)d_out;
    const size_t ACT = 8388608ULL;

    u16* ws16 = (u16*)d_ws;
    u16* xn   = ws16;
    u16* q    = ws16 + ACT;
    u16* k    = ws16 + 2 * ACT;
    u16* vT   = ws16 + 3 * ACT;
    u16* hbuf = ws16 + 2 * ACT;
    u16* wt   = ws16 + 6 * ACT;
    u16* x2   = q;
    (void)k;

    dim3 blk(256), blkp(576), blkh(512);
    transpose4_kernel<<<dim3(32, 32, 4), blk, 0, stream>>>(Wq, Wk, Wv, Wo, wt);
    ln_kernel<0><<<4096, blk, 0, stream>>>(x, ln1s, ln1b, xn);
    // fused QK: BT = [WqT;WkT] -> q, k buffers  (256x256 hybrid tile)
    gemm_ht<0, 0, 0, 1><<<dim3(16, 16), blkh, 0, stream>>>(xn, wt, q, nullptr, nullptr, 4096, 4096, 2048);
    // vT = WvT * xn^T -> vT[b][d][s]  (r15 proven)
    gemm_pc<0, 0, 0, 2, 1><<<dim3(32, 8), blkp, 0, stream>>>(wt + ACT, xn, vT, nullptr, nullptr, 2048, 4096, 2048);
    attn_kernel<<<dim3(16, 32), blk, 0, stream>>>(q, k, vT, xn); // ctx -> xn
    gemm_pc<1, 0, 0, 0, 0><<<dim3(16, 16), blkp, 0, stream>>>(xn, wt + 3 * (ACT >> 1), x2, bo, x, 4096, 2048, 2048);
    transpose_kernel<<<dim3(128, 32), blk, 0, stream>>>(W1, wt, 2048, 8192);
    ln_kernel<1><<<4096, blk, 0, stream>>>(x2, ln2s, ln2b, xn);
    // FFN1 (256x256 hybrid tile)
    gemm_ht<2, 0, 0, 0><<<dim3(32, 16), blkh, 0, stream>>>(xn, wt, hbuf, b1, nullptr, 4096, 8192, 2048);
    transpose_kernel<<<dim3(32, 128), blk, 0, stream>>>(W2, wt, 8192, 2048);
    gemm_pc<1, 1, 1, 0, 0><<<dim3(16, 16), blkp, 0, stream>>>(hbuf, wt, out, b2, x2, 4096, 2048, 8192);
}

// Round 19
// 618.854 us; speedup vs baseline: 1.1274x; 1.1274x over previous
//
#include <hip/hip_runtime.h>

typedef unsigned short u16;
typedef __attribute__((ext_vector_type(8))) short short8;
typedef __attribute__((ext_vector_type(8))) __bf16 bf16x8;
typedef __attribute__((ext_vector_type(4))) float f32x4;

#define DEV __device__ __forceinline__
#define SB() __builtin_amdgcn_sched_barrier(0)

DEV float bf2f(u16 u) {
    union { unsigned v; float f; } x; x.v = ((unsigned)u) << 16; return x.f;
}
DEV u16 f2bf(float f) {
    union { float f; unsigned v; } x; x.f = f;
    unsigned r = x.v + 0x7fff + ((x.v >> 16) & 1);
    return (u16)(r >> 16);
}

DEV f32x4 mfma16(short8 a, short8 b, f32x4 c) {
    return __builtin_amdgcn_mfma_f32_16x16x32_bf16(
        __builtin_bit_cast(bf16x8, a), __builtin_bit_cast(bf16x8, b), c, 0, 0, 0);
}

typedef const __attribute__((address_space(1))) void* gas_ptr;
typedef __attribute__((address_space(3))) void* las_ptr;

// ---------------- Batched transpose: 4x f32 [2048][2048] -> bf16 [2048][2048]^T ----------------
__global__ __launch_bounds__(256) void transpose4_kernel(
    const float* __restrict__ w0, const float* __restrict__ w1,
    const float* __restrict__ w2, const float* __restrict__ w3,
    u16* __restrict__ out)
{
    __shared__ u16 t[64][65];
    int tid = threadIdx.x, z = blockIdx.z;
    const float* in = (z == 0) ? w0 : (z == 1) ? w1 : (z == 2) ? w2 : w3;
    u16* op0 = out + (size_t)z * 4194304ULL;
    int bc = blockIdx.x * 64, br = blockIdx.y * 64;
    int r = tid >> 2, cs = (tid & 3) * 16;
    const float* ip = in + (size_t)(br + r) * 2048 + bc + cs;
    f32x4 v0 = *(const f32x4*)ip, v1 = *(const f32x4*)(ip + 4),
          v2 = *(const f32x4*)(ip + 8), v3 = *(const f32x4*)(ip + 12);
#pragma unroll
    for (int j = 0; j < 4; j++) {
        t[r][cs + j]      = f2bf(v0[j]);
        t[r][cs + 4 + j]  = f2bf(v1[j]);
        t[r][cs + 8 + j]  = f2bf(v2[j]);
        t[r][cs + 12 + j] = f2bf(v3[j]);
    }
    __syncthreads();
    int n = tid >> 2, ks = (tid & 3) * 16;
    short8 o0, o1;
#pragma unroll
    for (int j = 0; j < 8; j++) { o0[j] = (short)t[ks + j][n]; o1[j] = (short)t[ks + 8 + j][n]; }
    u16* op = op0 + (size_t)(bc + n) * 2048 + br + ks;
    *(short8*)op = o0;
    *(short8*)(op + 8) = o1;
}

// ---------------- Transpose: f32 [R][C] -> bf16 [C][R] ----------------
__global__ __launch_bounds__(256) void transpose_kernel(
    const float* __restrict__ in, u16* __restrict__ out, int R, int C)
{
    __shared__ u16 t[64][65];
    int tid = threadIdx.x;
    int bc = blockIdx.x * 64, br = blockIdx.y * 64;
    int r = tid >> 2, cs = (tid & 3) * 16;
    const float* ip = in + (size_t)(br + r) * C + bc + cs;
    f32x4 v0 = *(const f32x4*)ip, v1 = *(const f32x4*)(ip + 4),
          v2 = *(const f32x4*)(ip + 8), v3 = *(const f32x4*)(ip + 12);
#pragma unroll
    for (int j = 0; j < 4; j++) {
        t[r][cs + j]      = f2bf(v0[j]);
        t[r][cs + 4 + j]  = f2bf(v1[j]);
        t[r][cs + 8 + j]  = f2bf(v2[j]);
        t[r][cs + 12 + j] = f2bf(v3[j]);
    }
    __syncthreads();
    int n = tid >> 2, ks = (tid & 3) * 16;
    short8 o0, o1;
#pragma unroll
    for (int j = 0; j < 8; j++) { o0[j] = (short)t[ks + j][n]; o1[j] = (short)t[ks + 8 + j][n]; }
    u16* op = out + (size_t)(bc + n) * R + br + ks;
    *(short8*)op = o0;
    *(short8*)(op + 8) = o1;
}

// ---------------- LayerNorm ----------------
template<int INBF>
__global__ __launch_bounds__(256) void ln_kernel(
    const void* __restrict__ xp, const float* __restrict__ sc, const float* __restrict__ sh,
    u16* __restrict__ out)
{
    int row = blockIdx.x, tid = threadIdx.x;
    float f[8], sum = 0.f, ss = 0.f;
    if (INBF) {
        short8 v = *(const short8*)((const u16*)xp + (size_t)row * 2048 + tid * 8);
#pragma unroll
        for (int j = 0; j < 8; j++) f[j] = bf2f((u16)v[j]);
    } else {
        const f32x4* xr = (const f32x4*)((const float*)xp + (size_t)row * 2048 + tid * 8);
        f32x4 a = xr[0], b = xr[1];
#pragma unroll
        for (int j = 0; j < 4; j++) { f[j] = a[j]; f[4 + j] = b[j]; }
    }
#pragma unroll
    for (int j = 0; j < 8; j++) { sum += f[j]; ss += f[j] * f[j]; }
#pragma unroll
    for (int m = 1; m < 64; m <<= 1) { sum += __shfl_xor(sum, m, 64); ss += __shfl_xor(ss, m, 64); }
    __shared__ float red[8];
    int w = tid >> 6, l = tid & 63;
    if (l == 0) { red[w] = sum; red[4 + w] = ss; }
    __syncthreads();
    sum = red[0] + red[1] + red[2] + red[3];
    ss  = red[4] + red[5] + red[6] + red[7];
    float mean = sum * (1.f / 2048.f);
    float var  = ss * (1.f / 2048.f) - mean * mean;
    float rstd = rsqrtf(var + 1e-5f);
    const f32x4* sp = (const f32x4*)(sc + tid * 8);
    const f32x4* bp = (const f32x4*)(sh + tid * 8);
    f32x4 s0 = sp[0], s1 = sp[1], b0 = bp[0], b1 = bp[1];
    short8 o;
#pragma unroll
    for (int j = 0; j < 4; j++) {
        o[j]     = (short)f2bf((f[j] - mean) * rstd * s0[j] + b0[j]);
        o[4 + j] = (short)f2bf((f[4 + j] - mean) * rstd * s1[j] + b1[j]);
    }
    *(short8*)(out + (size_t)row * 2048 + tid * 8) = o;
}

// ---------------- Producer/consumer GEMM (BN=128, BK=64, ring-3) — champion (r11) ----------------
template<int EPI, int OUTF, int RESBF, int SPLITM, int SHAREB>
__global__ __launch_bounds__(576, 1) void gemm_pc(
    const u16* __restrict__ A, const u16* __restrict__ BT, void* __restrict__ Cp,
    const float* __restrict__ bias, const void* __restrict__ res, int M, int N, int K)
{
    __shared__ u16 As[3][256 * 64];
    __shared__ u16 Bs[3][128 * 64];
    int tid = threadIdx.x, l = tid & 63, w = tid >> 6;

    int nbx = gridDim.x, nby = gridDim.y;
    int nwg = nbx * nby;
    int orig = blockIdx.y * nbx + blockIdx.x;
    int wg = (orig & 7) * (nwg >> 3) + (orig >> 3);
    int bx, by;
    if (SHAREB) { bx = wg / nby; by = wg % nby; }
    else        { by = wg / nbx; bx = wg % nbx; }

    int mbase = by * 256, nbase = bx * 128;
    const u16* Ag = A + (size_t)mbase * K;
    const u16* Bg = BT + (size_t)nbase * K;
    int NT = K >> 6;

    if (w == 8) {
        auto pstage = [&](int s, int tt) {
#pragma unroll
            for (int g = 0; g < 32; g++) {
                int c = g * 64 + l;
                int r = c >> 3, ch = (c & 7) ^ (r & 7);
                __builtin_amdgcn_global_load_lds(
                    (gas_ptr)(Ag + (size_t)r * K + tt * 64 + ch * 8),
                    (las_ptr)&As[s][g * 512], 16, 0, 0);
            }
#pragma unroll
            for (int g = 0; g < 16; g++) {
                int c = g * 64 + l;
                int r = c >> 3, ch = (c & 7) ^ (r & 7);
                __builtin_amdgcn_global_load_lds(
                    (gas_ptr)(Bg + (size_t)r * K + tt * 64 + ch * 8),
                    (las_ptr)&Bs[s][g * 512], 16, 0, 0);
            }
        };
        pstage(0, 0); pstage(1, 1);
        asm volatile("s_waitcnt vmcnt(48)" ::: "memory");
        SB();
        __builtin_amdgcn_s_barrier();
        SB();
        for (int t = 0; t < NT; ++t) {
            if (t + 2 < NT) pstage((t + 2) % 3, t + 2);
            if (t + 1 < NT) {
                if (t + 2 < NT) { asm volatile("s_waitcnt vmcnt(48)" ::: "memory"); }
                else            { asm volatile("s_waitcnt vmcnt(0)"  ::: "memory"); }
            }
            SB();
            __builtin_amdgcn_s_barrier();
            SB();
        }
        return;
    }

    int wm = w >> 1, wn = w & 1;
    f32x4 acc[4][4];
#pragma unroll
    for (int i = 0; i < 4; i++)
#pragma unroll
        for (int j = 0; j < 4; j++) acc[i][j] = (f32x4){0.f, 0.f, 0.f, 0.f};

    __builtin_amdgcn_s_barrier();
    SB();
    int slot = 0;
    for (int t = 0; t < NT; ++t) {
        const u16* Ab = &As[slot][0];
        const u16* Bb = &Bs[slot][0];
        short8 af[2][4], bfr[2][4];
#pragma unroll
        for (int ks = 0; ks < 2; ks++) {
            int c = ks * 4 + (l >> 4);
#pragma unroll
            for (int i = 0; i < 4; i++) {
                int ra = wm * 64 + i * 16 + (l & 15);
                af[ks][i] = *(const short8*)&Ab[ra * 64 + ((c ^ (ra & 7)) << 3)];
                int rb = wn * 64 + i * 16 + (l & 15);
                bfr[ks][i] = *(const short8*)&Bb[rb * 64 + ((c ^ (rb & 7)) << 3)];
            }
        }
        __builtin_amdgcn_s_setprio(1);
#pragma unroll
        for (int ks = 0; ks < 2; ks++)
#pragma unroll
            for (int mi = 0; mi < 4; mi++)
#pragma unroll
                for (int ni = 0; ni < 4; ni++)
                    acc[mi][ni] = mfma16(af[ks][mi], bfr[ks][ni], acc[mi][ni]);
        __builtin_amdgcn_s_setprio(0);
        SB();
        __builtin_amdgcn_s_barrier();
        SB();
        slot = (slot == 2) ? 0 : slot + 1;
    }

#pragma unroll
    for (int mi = 0; mi < 4; mi++) {
#pragma unroll
        for (int ni = 0; ni < 4; ni++) {
            int col = nbase + wn * 64 + ni * 16 + (l & 15);
            float bval = (EPI != 0) ? bias[col] : 0.f;
#pragma unroll
            for (int r = 0; r < 4; r++) {
                int row = mbase + wm * 64 + mi * 16 + (l >> 4) * 4 + r;
                float v = acc[mi][ni][r];
                if (EPI == 1) {
                    size_t ridx = (size_t)row * N + col;
                    float rv = RESBF ? bf2f(((const u16*)res)[ridx]) : ((const float*)res)[ridx];
                    v += bval + rv;
                }
                if (EPI == 2) {
                    float tt = tanhf(0.7978845608028654f * ((v + bval) + 0.044715f * (v + bval) * (v + bval) * (v + bval)));
                    v = 0.5f * (v + bval) * (1.f + tt);
                }
                if (SPLITM == 1) {
                    ((u16*)Cp)[(size_t)(col >> 11) * 8388608ULL + (size_t)row * 2048 + (col & 2047)] = f2bf(v);
                } else if (SPLITM == 2) {
                    ((u16*)Cp)[(size_t)(col >> 11) * 4194304ULL + (size_t)row * 2048 + (col & 2047)] = f2bf(v);
                } else if (OUTF) {
                    ((float*)Cp)[(size_t)row * N + col] = v;
                } else {
                    ((u16*)Cp)[(size_t)row * N + col] = f2bf(v);
                }
            }
        }
    }
}

// ---------------- Causal flash attention: H=16, HD=128, S=2048 ----------------
// QBLK=128: 4 waves x 32 q-rows. KVBLK=64. V pre-transposed: VTg[(b*16+h)*128+d][key]
__global__ __launch_bounds__(256, 2) void attn_kernel(
    const u16* __restrict__ Q, const u16* __restrict__ Kp, const u16* __restrict__ VTg,
    u16* __restrict__ O)
{
    __shared__ u16 Ks[64 * 128];
    __shared__ u16 VT[128 * 64];
    __shared__ u16 Ps[4 * 2048];
    int tid = threadIdx.x, l = tid & 63, w = tid >> 6;
    int qtl = (int)gridDim.x - 1 - (int)blockIdx.x;
    int bh = blockIdx.y, b = bh >> 4, h = bh & 15;
    const float SCALE = 0.08838834764831845f;
    int qbase = qtl * 128;
    size_t bS = (size_t)b * 2048;
    const u16* vrow = VTg + (size_t)bh * 128 * 2048;

    short8 qf[2][4];
#pragma unroll
    for (int mg = 0; mg < 2; mg++) {
        int qrow = qbase + w * 32 + mg * 16 + (l & 15);
        const u16* qp = Q + (bS + qrow) * 2048 + h * 128 + (l >> 4) * 8;
#pragma unroll
        for (int ds = 0; ds < 4; ds++) qf[mg][ds] = *(const short8*)(qp + ds * 32);
    }
    float m_[2][4], l_[2][4];
    f32x4 o_[2][8];
#pragma unroll
    for (int mg = 0; mg < 2; mg++)
#pragma unroll
        for (int r = 0; r < 4; r++) { m_[mg][r] = -1e30f; l_[mg][r] = 0.f; }
#pragma unroll
    for (int mg = 0; mg < 2; mg++)
#pragma unroll
        for (int d = 0; d < 8; d++) o_[mg][d] = (f32x4){0.f, 0.f, 0.f, 0.f};

    int ktmax = 2 * qtl + 1;
    for (int kt = 0; kt <= ktmax; ++kt) {
        int kbase = kt * 64;
#pragma unroll
        for (int it = 0; it < 4; ++it) {
            int slot = it * 256 + tid;
            int key = slot >> 4, dseg = slot & 15;
            short8 kv = *(const short8*)(Kp + (bS + kbase + key) * 2048 + h * 128 + dseg * 8);
            int kidx = ((key * 256 + dseg * 16) ^ ((key & 7) << 4)) >> 1;
            *(short8*)&Ks[kidx] = kv;
            int d = slot >> 3, k8 = slot & 7;
            short8 vv = *(const short8*)(vrow + (size_t)d * 2048 + kbase + k8 * 8);
            int vidx = ((d * 128 + k8 * 16) ^ ((d & 7) << 4)) >> 1;
            *(short8*)&VT[vidx] = vv;
        }
        __syncthreads();

        f32x4 s[2][4];
#pragma unroll
        for (int mg = 0; mg < 2; mg++)
#pragma unroll
            for (int kg = 0; kg < 4; kg++) s[mg][kg] = (f32x4){0.f, 0.f, 0.f, 0.f};
        __builtin_amdgcn_s_setprio(1);
#pragma unroll
        for (int kg = 0; kg < 4; kg++) {
            int key0 = kg * 16 + (l & 15);
#pragma unroll
            for (int ds = 0; ds < 4; ds++) {
                int i0 = ((key0 * 256 + ds * 64 + (l >> 4) * 16) ^ ((key0 & 7) << 4)) >> 1;
                short8 kb = *(const short8*)&Ks[i0];
                s[0][kg] = mfma16(qf[0][ds], kb, s[0][kg]);
                s[1][kg] = mfma16(qf[1][ds], kb, s[1][kg]);
            }
        }
        __builtin_amdgcn_s_setprio(0);

        bool domask = (kbase + 63) > qbase;
        float alpha[2][4];
        u16* Pw = &Ps[w * 2048];
#pragma unroll
        for (int mg = 0; mg < 2; mg++) {
#pragma unroll
            for (int r = 0; r < 4; r++) {
                int qrow = qbase + w * 32 + mg * 16 + (l >> 4) * 4 + r;
                float aa[4];
#pragma unroll
                for (int kg = 0; kg < 4; kg++) {
                    float a = s[mg][kg][r] * SCALE;
                    if (domask && (kbase + kg * 16 + (l & 15)) > qrow) a = -1e30f;
                    aa[kg] = a;
                }
                float mx = fmaxf(fmaxf(aa[0], aa[1]), fmaxf(aa[2], aa[3]));
                mx = fmaxf(mx, __shfl_xor(mx, 1, 64));
                mx = fmaxf(mx, __shfl_xor(mx, 2, 64));
                mx = fmaxf(mx, __shfl_xor(mx, 4, 64));
                mx = fmaxf(mx, __shfl_xor(mx, 8, 64));
                float mn = fmaxf(m_[mg][r], mx);
                float al = __expf(m_[mg][r] - mn);
                m_[mg][r] = mn;
                float p[4], rs = 0.f;
#pragma unroll
                for (int kg = 0; kg < 4; kg++) { p[kg] = __expf(aa[kg] - mn); rs += p[kg]; }
                rs += __shfl_xor(rs, 1, 64);
                rs += __shfl_xor(rs, 2, 64);
                rs += __shfl_xor(rs, 4, 64);
                rs += __shfl_xor(rs, 8, 64);
                l_[mg][r] = l_[mg][r] * al + rs;
                alpha[mg][r] = al;
#pragma unroll
                for (int kg = 0; kg < 4; kg++) {
                    int col = kg * 16 + (l & 15);
                    int lp = ((l >> 4) * 4 + r) | (((col >> 3) & 3) << 4);
                    Pw[(mg * 2 + (col >> 5)) * 512 + lp * 8 + (col & 7)] = f2bf(p[kg]);
                }
            }
        }
#pragma unroll
        for (int mg = 0; mg < 2; mg++)
#pragma unroll
            for (int dblk = 0; dblk < 8; dblk++)
#pragma unroll
                for (int r = 0; r < 4; r++) o_[mg][dblk][r] *= alpha[mg][r];

        __builtin_amdgcn_s_setprio(1);
#pragma unroll
        for (int kk = 0; kk < 2; kk++) {
            short8 pa0 = *(const short8*)&Pw[(0 * 2 + kk) * 512 + l * 8];
            short8 pa1 = *(const short8*)&Pw[(1 * 2 + kk) * 512 + l * 8];
#pragma unroll
            for (int dblk = 0; dblk < 8; dblk++) {
                int d = dblk * 16 + (l & 15);
                int iv = ((d * 128 + kk * 64 + (l >> 4) * 16) ^ ((d & 7) << 4)) >> 1;
                short8 vb = *(const short8*)&VT[iv];
                o_[0][dblk] = mfma16(pa0, vb, o_[0][dblk]);
                o_[1][dblk] = mfma16(pa1, vb, o_[1][dblk]);
            }
        }
        __builtin_amdgcn_s_setprio(0);
        __syncthreads();
    }

#pragma unroll
    for (int mg = 0; mg < 2; mg++) {
#pragma unroll
        for (int dblk = 0; dblk < 8; dblk++) {
#pragma unroll
            for (int r = 0; r < 4; r++) {
                int qrow = qbase + w * 32 + mg * 16 + (l >> 4) * 4 + r;
                float v = o_[mg][dblk][r] / l_[mg][r];
                O[(bS + qrow) * 2048 + h * 128 + dblk * 16 + (l & 15)] = f2bf(v);
            }
        }
    }
}

extern "C" void kernel_launch(void* const* d_in, const int* in_sizes, int n_in,
                              void* d_out, int out_size, void* d_ws, size_t ws_size,
                              hipStream_t stream)
{
    const float* x    = (const float*)d_in[0];
    const float* ln1s = (const float*)d_in[1];
    const float* ln1b = (const float*)d_in[2];
    const float* Wq   = (const float*)d_in[3];
    const float* Wk   = (const float*)d_in[4];
    const float* Wv   = (const float*)d_in[5];
    const float* Wo   = (const float*)d_in[6];
    const float* bo   = (const float*)d_in[7];
    const float* ln2s = (const float*)d_in[8];
    const float* ln2b = (const float*)d_in[9];
    const float* W1   = (const float*)d_in[10];
    const float* b1   = (const float*)d_in[11];
    const float* W2   = (const float*)d_in[12];
    const float* b2   = (const float*)d_in[13];
    float* out = (float*)d_out;
    const size_t ACT = 8388608ULL;

    u16* ws16 = (u16*)d_ws;
    u16* xn   = ws16;
    u16* q    = ws16 + ACT;
    u16* k    = ws16 + 2 * ACT;
    u16* vT   = ws16 + 3 * ACT;
    u16* hbuf = ws16 + 2 * ACT;
    u16* wt   = ws16 + 6 * ACT;
    u16* x2   = q;
    (void)k;

    dim3 blk(256), blkp(576);
    transpose4_kernel<<<dim3(32, 32, 4), blk, 0, stream>>>(Wq, Wk, Wv, Wo, wt);
    ln_kernel<0><<<4096, blk, 0, stream>>>(x, ln1s, ln1b, xn);
    // fused QK: BT = [WqT;WkT] -> q, k buffers
    gemm_pc<0, 0, 0, 1, 1><<<dim3(32, 16), blkp, 0, stream>>>(xn, wt, q, nullptr, nullptr, 4096, 4096, 2048);
    // vT = WvT * xn^T -> vT[b][d][s]
    gemm_pc<0, 0, 0, 2, 1><<<dim3(32, 8), blkp, 0, stream>>>(wt + ACT, xn, vT, nullptr, nullptr, 2048, 4096, 2048);
    attn_kernel<<<dim3(16, 32), blk, 0, stream>>>(q, k, vT, xn); // ctx -> xn
    gemm_pc<1, 0, 0, 0, 0><<<dim3(16, 16), blkp, 0, stream>>>(xn, wt + 3 * (ACT >> 1), x2, bo, x, 4096, 2048, 2048);
    transpose_kernel<<<dim3(128, 32), blk, 0, stream>>>(W1, wt, 2048, 8192);
    ln_kernel<1><<<4096, blk, 0, stream>>>(x2, ln2s, ln2b, xn);
    gemm_pc<2, 0, 0, 0, 1><<<dim3(64, 16), blkp, 0, stream>>>(xn, wt, hbuf, b1, nullptr, 4096, 8192, 2048);
    transpose_kernel<<<dim3(32, 128), blk, 0, stream>>>(W2, wt, 8192, 2048);
    gemm_pc<1, 1, 1, 0, 0><<<dim3(16, 16), blkp, 0, stream>>>(hbuf, wt, out, b2, x2, 4096, 2048, 8192);
}